// Round 12
// baseline (202.749 us; speedup 1.0000x reference)
//
#include <hip/hip_runtime.h>
#include <math.h>

// B=8, T=2048, C=1024, H=64.
// *** MEASUREMENT ROUND (time-dilation) ***: identical to round-11 kernels,
// but proj_kernel is launched 4x (idempotent: rewrites the same q/k/vt;
// attn runs after all four). P_proj = (dur - dur_r11)/3, warm-cache biased
// slightly low. Localizes the unexplained ~87us between proj and attn,
// since both kernels are individually <41us and invisible under the
// harness fill in rocprof top-5.
//  (1) wswz: W pre-swizzle + per-tile counter reset
//  (2) proj x4: bf16 MFMA projection, 32 rows/block (r11)
//  (3) attn: split-KV flash attn + in-kernel combine (r10-proven)
namespace {
constexpr int BATCH = 8;
constexpr int TSEQ  = 2048;
constexpr int CDIM  = 1024;
constexpr int HDIM  = 64;
constexpr int MROWS = BATCH * TSEQ;         // 16384
constexpr int NTILE = 128;                  // 16-row q-tiles per batch
constexpr int NSLC  = 8;                    // KV slices per q-tile
// fold softmax scale (1/8) AND log2(e) into Wq so softmax can use exp2
constexpr float QSCALE = 0.125f * 1.4426950408889634f;
}

typedef __attribute__((ext_vector_type(4))) float  f32x4;
typedef __attribute__((ext_vector_type(8))) short  s16x8;   // 8 bf16 (4 VGPRs)
typedef __attribute__((ext_vector_type(4))) unsigned short u16x4;

__device__ __forceinline__ unsigned short f2bf(float f) {
    union { float f; unsigned u; } c{f};
    unsigned r = c.u + 0x7FFFu + ((c.u >> 16) & 1u);   // RNE
    return (unsigned short)(r >> 16);
}
__device__ __forceinline__ float bf2f(unsigned short h) {
    union { unsigned u; float f; } c;
    c.u = (unsigned)h << 16;
    return c.f;
}

// ---- coherence-point (IC) ops for the partials handoff (r6/r10-proven) ----
__device__ __forceinline__ void st_sys_b16(unsigned short* p, unsigned v) {
    asm volatile("global_store_short %0, %1, off sc0 sc1"
                 :: "v"((unsigned long long)(uintptr_t)p), "v"(v) : "memory");
}
__device__ __forceinline__ void st_sys_b32(float* p, float v) {
    asm volatile("global_store_dword %0, %1, off sc0 sc1"
                 :: "v"((unsigned long long)(uintptr_t)p), "v"(v) : "memory");
}

// --------------------------------------------------------------------------
// W pre-swizzle + per-tile counter reset.
// swz[((ksg*12+tn)*64+lane)*8+j] = W'[k=ksg*32+(lane>>4)*8+j][n=tn*16+(lane&15)]
// cnt layout: [0..255] per-tile (b*32+t). ws re-poisoned each iteration ->
// must re-zero every launch.
// --------------------------------------------------------------------------
__global__ __launch_bounds__(256)
void wswz_kernel(const float* __restrict__ Wk, const float* __restrict__ Wq,
                 const float* __restrict__ Wv, unsigned short* __restrict__ swz,
                 unsigned* __restrict__ cnt)
{
    if (blockIdx.x == 0) cnt[threadIdx.x] = 0u;        // 256 == BATCH*32

    const int idx  = blockIdx.x * 256 + threadIdx.x;   // 0 .. 196607
    const int j    = idx & 7;
    const int lane = (idx >> 3) & 63;
    const int rest = idx >> 9;          // ksg*12 + tn
    const int tn   = rest % 12;
    const int ksg  = rest / 12;
    const int kk   = ksg * 32 + (lane >> 4) * 8 + j;
    const int n    = tn * 16 + (lane & 15);
    float val;
    if (n < 64)       val = Wq[kk * HDIM + n] * QSCALE;
    else if (n < 128) val = Wk[kk * HDIM + (n - 64)];
    else              val = Wv[kk * HDIM + (n - 128)];
    swz[idx] = f2bf(val);
}

// --------------------------------------------------------------------------
// Projection, 32 rows/block (r11, verbatim): 512 blocks x 256 thr;
// LDS 64 KB -> 2 blocks/CU. XOR bank-swizzle col^((row&7)<<3).
// --------------------------------------------------------------------------
__global__ __launch_bounds__(256, 2)
void proj_kernel(const float* __restrict__ x, const unsigned short* __restrict__ swz,
                 unsigned short* __restrict__ q, unsigned short* __restrict__ k,
                 unsigned short* __restrict__ vt)
{
    __shared__ unsigned short xl[32][1024];   // exactly 64 KB

    const int tid  = threadIdx.x;
    const int lane = tid & 63, wave = tid >> 6;
    const int quad = lane >> 4, l15 = lane & 15;
    const int cq   = wave;          // 48-col quarter
    const int m0   = blockIdx.x * 32;

    // phase 1: x slab -> LDS bf16, two 16-row passes
    #pragma unroll
    for (int pass = 0; pass < 2; ++pass) {
        const float* xb = x + (size_t)(m0 + pass * 16) * CDIM;
        float4 t[16];
        #pragma unroll
        for (int i = 0; i < 16; ++i)
            t[i] = *(const float4*)(xb + i * 1024 + tid * 4);   // independent
        #pragma unroll
        for (int i = 0; i < 16; ++i) {
            const int row = pass * 16 + i;
            const int col = (tid * 4) ^ ((row & 7) << 3);        // XOR swizzle
            u16x4 p;
            p[0] = f2bf(t[i].x); p[1] = f2bf(t[i].y);
            p[2] = f2bf(t[i].z); p[3] = f2bf(t[i].w);
            *(u16x4*)&xl[row][col] = p;
        }
    }
    __syncthreads();

    // phase 2: 32 K-steps, B prefetched 1 ahead, 2 row-groups per fragment
    f32x4 acc[2][3] = {};
    const unsigned short* bp = swz + ((size_t)(cq * 3) * 64 + lane) * 8;
    s16x8 b0 = *(const s16x8*)(bp);
    s16x8 b1 = *(const s16x8*)(bp + 512);
    s16x8 b2 = *(const s16x8*)(bp + 1024);
    bp += 6144;

    const int swzl = (l15 & 7) << 3;          // row-dependent col XOR
    #pragma unroll
    for (int ks = 0; ks < 32; ++ks) {
        s16x8 nb0, nb1, nb2;
        if (ks < 31) {
            nb0 = *(const s16x8*)(bp);
            nb1 = *(const s16x8*)(bp + 512);
            nb2 = *(const s16x8*)(bp + 1024);
            bp += 6144;
        }
        const int c = (ks * 32 + quad * 8) ^ swzl;
        const s16x8 a0 = *(const s16x8*)&xl[l15][c];
        const s16x8 a1 = *(const s16x8*)&xl[16 + l15][c];
        acc[0][0] = __builtin_amdgcn_mfma_f32_16x16x32_bf16(a0, b0, acc[0][0], 0, 0, 0);
        acc[1][0] = __builtin_amdgcn_mfma_f32_16x16x32_bf16(a1, b0, acc[1][0], 0, 0, 0);
        acc[0][1] = __builtin_amdgcn_mfma_f32_16x16x32_bf16(a0, b1, acc[0][1], 0, 0, 0);
        acc[1][1] = __builtin_amdgcn_mfma_f32_16x16x32_bf16(a1, b1, acc[1][1], 0, 0, 0);
        acc[0][2] = __builtin_amdgcn_mfma_f32_16x16x32_bf16(a0, b2, acc[0][2], 0, 0, 0);
        acc[1][2] = __builtin_amdgcn_mfma_f32_16x16x32_bf16(a1, b2, acc[1][2], 0, 0, 0);
        if (ks < 31) { b0 = nb0; b1 = nb1; b2 = nb2; }
    }

    // epilogue: C/D row = g*16 + quad*4 + r, col = cq*48 + t*16 + l15
    #pragma unroll
    for (int g = 0; g < 2; ++g) {
        const int rowg = m0 + g * 16 + quad * 4;
        #pragma unroll
        for (int t = 0; t < 3; ++t) {
            const int n = cq * 48 + t * 16 + l15;
            if (n < 64) {
                #pragma unroll
                for (int r = 0; r < 4; ++r)
                    q[(size_t)(rowg + r) * HDIM + n] = f2bf(acc[g][t][r]);
            } else if (n < 128) {
                #pragma unroll
                for (int r = 0; r < 4; ++r)
                    k[(size_t)(rowg + r) * HDIM + (n - 64)] = f2bf(acc[g][t][r]);
            } else {
                const int h  = n - 128;
                const int bb = rowg >> 11, tl = rowg & 2047;
                u16x4 pv;
                #pragma unroll
                for (int r = 0; r < 4; ++r) pv[r] = f2bf(acc[g][t][r]);
                *(u16x4*)(vt + ((size_t)bb * HDIM + h) * TSEQ + tl) = pv;
            }
        }
    }
}

// Combine one 64-row tile (b,t) (r10-proven, verbatim).
__device__ __forceinline__ void combine_tile(
    const unsigned short* __restrict__ Opart, const float* __restrict__ lpart,
    float* __restrict__ out, int b, int t, int valid, int tid)
{
    float a[4][4] = {{0.f}};
    float lv[4] = {0.f, 0.f, 0.f, 0.f};
    size_t lbase[4]; int rr[4], c4v[4];
    #pragma unroll
    for (int i = 0; i < 4; ++i) {
        const int item = i * 256 + tid;        // 0..1023
        rr[i]  = item >> 4;                    // tile row 0..63
        c4v[i] = (item & 15) << 2;             // col group
        const int ti16 = t * 4 + (rr[i] >> 4);
        lbase[i] = ((size_t)b * NTILE + ti16) * NSLC * 16 + (rr[i] & 15);
    }
    for (int s = 0; s < valid; ++s) {
        unsigned long long o0, o1, o2, o3;
        float f0, f1, f2, f3;
        const unsigned long long A0 = (unsigned long long)(uintptr_t)(Opart + (lbase[0] + (size_t)s * 16) * HDIM + c4v[0]);
        const unsigned long long A1 = (unsigned long long)(uintptr_t)(Opart + (lbase[1] + (size_t)s * 16) * HDIM + c4v[1]);
        const unsigned long long A2 = (unsigned long long)(uintptr_t)(Opart + (lbase[2] + (size_t)s * 16) * HDIM + c4v[2]);
        const unsigned long long A3 = (unsigned long long)(uintptr_t)(Opart + (lbase[3] + (size_t)s * 16) * HDIM + c4v[3]);
        const unsigned long long L0 = (unsigned long long)(uintptr_t)(lpart + lbase[0] + (size_t)s * 16);
        const unsigned long long L1 = (unsigned long long)(uintptr_t)(lpart + lbase[1] + (size_t)s * 16);
        const unsigned long long L2 = (unsigned long long)(uintptr_t)(lpart + lbase[2] + (size_t)s * 16);
        const unsigned long long L3 = (unsigned long long)(uintptr_t)(lpart + lbase[3] + (size_t)s * 16);
        asm volatile(
            "global_load_dwordx2 %0, %8, off sc0 sc1\n\t"
            "global_load_dwordx2 %1, %9, off sc0 sc1\n\t"
            "global_load_dwordx2 %2, %10, off sc0 sc1\n\t"
            "global_load_dwordx2 %3, %11, off sc0 sc1\n\t"
            "global_load_dword %4, %12, off sc0 sc1\n\t"
            "global_load_dword %5, %13, off sc0 sc1\n\t"
            "global_load_dword %6, %14, off sc0 sc1\n\t"
            "global_load_dword %7, %15, off sc0 sc1\n\t"
            "s_waitcnt vmcnt(0)"
            : "=&v"(o0), "=&v"(o1), "=&v"(o2), "=&v"(o3),
              "=&v"(f0), "=&v"(f1), "=&v"(f2), "=&v"(f3)
            : "v"(A0), "v"(A1), "v"(A2), "v"(A3),
              "v"(L0), "v"(L1), "v"(L2), "v"(L3)
            : "memory");
        #pragma unroll
        for (int j = 0; j < 4; ++j) {
            a[0][j] += bf2f((unsigned short)(o0 >> (16 * j)));
            a[1][j] += bf2f((unsigned short)(o1 >> (16 * j)));
            a[2][j] += bf2f((unsigned short)(o2 >> (16 * j)));
            a[3][j] += bf2f((unsigned short)(o3 >> (16 * j)));
        }
        lv[0] += f0; lv[1] += f1; lv[2] += f2; lv[3] += f3;
    }
    #pragma unroll
    for (int i = 0; i < 4; ++i) {
        const float inv = 1.f / lv[i];
        float4 o = {a[i][0] * inv, a[i][1] * inv, a[i][2] * inv, a[i][3] * inv};
        const int row = b * TSEQ + t * 64 + rr[i];
        *(float4*)(out + (size_t)row * HDIM + c4v[i]) = o;
    }
}

// --------------------------------------------------------------------------
// Flash attention pass + in-kernel combine (r10-proven, verbatim).
// --------------------------------------------------------------------------
__global__ __launch_bounds__(256, 4)
void attn_kernel(const unsigned short* __restrict__ q, const unsigned short* __restrict__ k,
                 const unsigned short* __restrict__ vt,
                 unsigned short* __restrict__ Opart, float* __restrict__ lpart,
                 unsigned* __restrict__ cnt, float* __restrict__ out)
{
    __shared__ unsigned short Kb[4096];        // 8 KB: chunk K, fragment order
    __shared__ unsigned short Vb[4096];        // 8 KB: chunk V^T, fragment order
    __shared__ unsigned short Pl[4][16][72];   // per-wave P transform (9.2 KB)
    __shared__ int sflag;

    const int tid  = threadIdx.x;
    const int lane = tid & 63, wave = tid >> 6;
    const int quad = lane >> 4, l15 = lane & 15;
    const int b    = blockIdx.y;
    const int p    = blockIdx.x >> 3;          // pair 0..15
    const int s    = blockIdx.x & 7;           // KV slice

    const unsigned short* qb  = q  + (size_t)b * TSEQ * HDIM;
    const unsigned short* kb  = k  + (size_t)b * TSEQ * HDIM;
    const unsigned short* vtb = vt + (size_t)b * HDIM * TSEQ;

    // staging map: thread covers groups g = tid, tid+256
    const int rs = tid >> 3, cgs = tid & 7;
    const int d0 = (((cgs >> 2) * 4 + (rs >> 4)) * 64 + (cgs & 3) * 16 + (rs & 15)) * 8;
    const int rs2 = rs + 32;
    const int d1 = (((cgs >> 2) * 4 + (rs2 >> 4)) * 64 + (cgs & 3) * 16 + (rs2 & 15)) * 8;

    for (int tsel = 0; tsel < 2; ++tsel) {
        const int t   = (tsel == 0) ? p : 31 - p;
        const int m0w = t * 64 + wave * 16;
        const int nt  = t + 1;                 // chunks 0..t

        if (s < nt) {                          // block-uniform branch
            const s16x8 aq0 = *(const s16x8*)(qb + (size_t)(m0w + l15) * HDIM + quad * 8);
            const s16x8 aq1 = *(const s16x8*)(qb + (size_t)(m0w + l15) * HDIM + 32 + quad * 8);

            f32x4 O[4] = {};
            float l_lane[4] = {0.f, 0.f, 0.f, 0.f};

            {   // stage first chunk
                const int n0 = s * 64;
                const s16x8 ka = *(const s16x8*)(kb + (size_t)(n0 + rs) * HDIM + cgs * 8);
                const s16x8 kc = *(const s16x8*)(kb + (size_t)(n0 + rs2) * HDIM + cgs * 8);
                const s16x8 va = *(const s16x8*)(vtb + (size_t)rs * TSEQ + n0 + cgs * 8);
                const s16x8 vc = *(const s16x8*)(vtb + (size_t)rs2 * TSEQ + n0 + cgs * 8);
                *(s16x8*)&Kb[d0] = ka; *(s16x8*)&Kb[d1] = kc;
                *(s16x8*)&Vb[d0] = va; *(s16x8*)&Vb[d1] = vc;
            }
            __syncthreads();

            for (int c = s; c < nt; c += 8) {
                const bool pref = (c + 8) < nt;   // block-uniform
                s16x8 ka, kc, va, vc;
                if (pref) {                        // next chunk into registers now
                    const int n0n = (c + 8) * 64;
                    ka = *(const s16x8*)(kb + (size_t)(n0n + rs) * HDIM + cgs * 8);
                    kc = *(const s16x8*)(kb + (size_t)(n0n + rs2) * HDIM + cgs * 8);
                    va = *(const s16x8*)(vtb + (size_t)rs * TSEQ + n0n + cgs * 8);
                    vc = *(const s16x8*)(vtb + (size_t)rs2 * TSEQ + n0n + cgs * 8);
                }

                // ---- S = Q K^T from Kb ----
                f32x4 S[4] = {};
                #pragma unroll
                for (int st = 0; st < 4; ++st) {
                    const s16x8 k0 = *(const s16x8*)&Kb[(st * 64 + lane) * 8];
                    const s16x8 k1 = *(const s16x8*)&Kb[((4 + st) * 64 + lane) * 8];
                    S[st] = __builtin_amdgcn_mfma_f32_16x16x32_bf16(aq0, k0, S[st], 0, 0, 0);
                    S[st] = __builtin_amdgcn_mfma_f32_16x16x32_bf16(aq1, k1, S[st], 0, 0, 0);
                }
                __syncthreads();                   // bar1: all waves done with Kb
                if (pref) { *(s16x8*)&Kb[d0] = ka; *(s16x8*)&Kb[d1] = kc; }

                // ---- softmax (no-max, exp2 domain) ----
                const int n0 = c * 64;
                if (c == t) {                      // diagonal chunk: causal mask
                    const int rowbase = m0w + quad * 4;
                    #pragma unroll
                    for (int st = 0; st < 4; ++st) {
                        const int col = n0 + st * 16 + l15;
                        #pragma unroll
                        for (int r = 0; r < 4; ++r) {
                            const float pv = (col > rowbase + r) ? 0.f : exp2f(S[st][r]);
                            S[st][r] = pv;
                            l_lane[r] += pv;
                        }
                    }
                } else {
                    #pragma unroll
                    for (int st = 0; st < 4; ++st)
                        #pragma unroll
                        for (int r = 0; r < 4; ++r) {
                            const float pv = exp2f(S[st][r]);
                            S[st][r] = pv;
                            l_lane[r] += pv;
                        }
                }

                // P: C-layout -> A-layout via per-wave LDS slice
                #pragma unroll
                for (int st = 0; st < 4; ++st)
                    #pragma unroll
                    for (int r = 0; r < 4; ++r)
                        Pl[wave][quad * 4 + r][st * 16 + l15] = f2bf(S[st][r]);
                const s16x8 pa0 = *(const s16x8*)&Pl[wave][l15][quad * 8];
                const s16x8 pa1 = *(const s16x8*)&Pl[wave][l15][32 + quad * 8];

                // ---- O += P V from Vb ----
                #pragma unroll
                for (int hst = 0; hst < 4; ++hst) {
                    const s16x8 v0 = *(const s16x8*)&Vb[(hst * 64 + lane) * 8];
                    const s16x8 v1 = *(const s16x8*)&Vb[((4 + hst) * 64 + lane) * 8];
                    O[hst] = __builtin_amdgcn_mfma_f32_16x16x32_bf16(pa0, v0, O[hst], 0, 0, 0);
                    O[hst] = __builtin_amdgcn_mfma_f32_16x16x32_bf16(pa1, v1, O[hst], 0, 0, 0);
                }
                __syncthreads();                   // bar2: Vb free, Kb writes fenced
                if (pref) { *(s16x8*)&Vb[d0] = va; *(s16x8*)&Vb[d1] = vc; }
            }

            // l reduction across the 16 lanes of each row group
            #pragma unroll
            for (int off = 1; off < 16; off <<= 1)
                #pragma unroll
                for (int r = 0; r < 4; ++r)
                    l_lane[r] += __shfl_xor(l_lane[r], off);

            // wave partial -> workspace, WRITE-THROUGH (sc0 sc1)
            const int ti16 = t * 4 + wave;
            const size_t pi = ((size_t)b * NTILE + ti16) * NSLC + s;
            #pragma unroll
            for (int hst = 0; hst < 4; ++hst)
                #pragma unroll
                for (int r = 0; r < 4; ++r)
                    st_sys_b16(Opart + (pi * 16 + quad * 4 + r) * HDIM + hst * 16 + l15,
                               (unsigned)f2bf(O[hst][r]));
            if (l15 == 0) {
                #pragma unroll
                for (int r = 0; r < 4; ++r)
                    st_sys_b32(lpart + pi * 16 + quad * 4 + r, l_lane[r]);
            }
            asm volatile("s_waitcnt vmcnt(0)" ::: "memory");  // stores at IC
            __syncthreads();

            // ---- signal tile completion; last finisher combines ----
            const int valid = (nt < NSLC) ? nt : NSLC;
            if (tid == 0) {
                const unsigned old = __hip_atomic_fetch_add(
                    &cnt[b * 32 + t], 1u, __ATOMIC_RELAXED,
                    __HIP_MEMORY_SCOPE_AGENT);
                sflag = (old == (unsigned)(valid - 1));
            }
            __syncthreads();
            if (sflag)
                combine_tile(Opart, lpart, out, b, t, valid, tid);
        }
    }
}

// ---------------------------------------------------------------------------
extern "C" void kernel_launch(void* const* d_in, const int* in_sizes, int n_in,
                              void* d_out, int out_size, void* d_ws, size_t ws_size,
                              hipStream_t stream) {
    const float* x  = (const float*)d_in[0];
    const float* Wk = (const float*)d_in[1];
    const float* Wq = (const float*)d_in[2];
    const float* Wv = (const float*)d_in[3];
    float* out = (float*)d_out;

    // ws layout: swz | q | k | vt | Opart (bf16) | lpart (fp32) | cnt (256 u32)
    unsigned short* swz = (unsigned short*)d_ws;            // 196608 elems
    unsigned short* qw  = swz + 196608;
    unsigned short* kw  = qw + (size_t)MROWS * HDIM;
    unsigned short* vtw = kw + (size_t)MROWS * HDIM;
    unsigned short* Opart = vtw + (size_t)MROWS * HDIM;     // 8192*16*64 bf16
    float* lpart = (float*)(Opart + (size_t)BATCH * NTILE * NSLC * 16 * HDIM);
    unsigned* cnt = (unsigned*)(lpart + (size_t)BATCH * NTILE * NSLC * 16);

    wswz_kernel<<<dim3(768), 256, 0, stream>>>(Wk, Wq, Wv, swz, cnt);
    // MEASUREMENT: proj x4 (idempotent). P = (dur - dur_r11)/3.
    proj_kernel<<<dim3(MROWS / 32), 256, 0, stream>>>(x, swz, qw, kw, vtw);
    proj_kernel<<<dim3(MROWS / 32), 256, 0, stream>>>(x, swz, qw, kw, vtw);
    proj_kernel<<<dim3(MROWS / 32), 256, 0, stream>>>(x, swz, qw, kw, vtw);
    proj_kernel<<<dim3(MROWS / 32), 256, 0, stream>>>(x, swz, qw, kw, vtw);
    attn_kernel<<<dim3(16 * NSLC, BATCH), 256, 0, stream>>>(qw, kw, vtw,
                                                            Opart, lpart, cnt, out);
}